// Round 16
// baseline (125.377 us; speedup 1.0000x reference)
//
#include <hip/hip_runtime.h>
#include <hip/hip_bf16.h>

#define N_NODES 10000
#define KP      10240   // K padded; xwt pad slabs are ZERO
#define F       128
#define SPLITS  8
#define KSPLIT  1280    // KP / SPLITS
#define BK      64
#define TPS     20      // tiles per split (= 5 quads)
#define BM      64
#define MBLK    157     // ceil(10000/64)
#define PROWS   10048   // MBLK*64
#define ALIM    (100000000u - 4u)   // N*N - 4

typedef float  f32x4  __attribute__((ext_vector_type(4)));
typedef short  bf16x8 __attribute__((ext_vector_type(8)));
typedef short  s16x8  __attribute__((ext_vector_type(8)));
typedef short  s16x4  __attribute__((ext_vector_type(4)));

static __device__ __forceinline__ unsigned short f2bf(float f) {
    unsigned u = __builtin_bit_cast(unsigned, f);
    u += 0x7FFFu + ((u >> 16) & 1u);
    return (unsigned short)(u >> 16);
}

static __device__ __forceinline__ s16x4 pack4(f32x4 v) {
    s16x4 r;
    r[0] = (short)f2bf(v[0]); r[1] = (short)f2bf(v[1]);
    r[2] = (short)f2bf(v[2]); r[3] = (short)f2bf(v[3]);
    return r;
}

// ---------------------------------------------------------------------------
// Kernel 1: xwt = (X @ W1)^T bf16, tiled+swizzled for direct global_load_lds:
//   16B unit u = kc2*512 + ct*64 + c*4 + ku within each 16KB slab-pair,
//   STORED at position p = u ^ (c&7).  (R8/R9-proven layout.)
// ---------------------------------------------------------------------------
__global__ __launch_bounds__(256) void k_xw(const float* __restrict__ x,
                                            const float* __restrict__ W1,
                                            unsigned short* __restrict__ xwt) {
    __shared__ float xs[16][128];
    __shared__ unsigned short ts[16][136];
    const int t  = threadIdx.x;
    const int nb = blockIdx.x * 16;

    #pragma unroll
    for (int i = 0; i < 2; ++i) {
        int idx = t + i * 256;
        int n   = idx >> 5;
        int c4  = idx & 31;
        int gn  = nb + n; if (gn > N_NODES - 1) gn = N_NODES - 1;
        f32x4 v = *reinterpret_cast<const f32x4*>(x + (size_t)gn * F + c4 * 4);
        *reinterpret_cast<f32x4*>(&xs[n][c4 * 4]) = v;
    }
    __syncthreads();

    const int f  = t & 127;
    const int ng = t >> 7;
    float acc[8] = {0.f, 0.f, 0.f, 0.f, 0.f, 0.f, 0.f, 0.f};

    for (int c4 = 0; c4 < 32; ++c4) {
        float w0 = W1[(4 * c4 + 0) * F + f];
        float w1 = W1[(4 * c4 + 1) * F + f];
        float w2 = W1[(4 * c4 + 2) * F + f];
        float w3 = W1[(4 * c4 + 3) * F + f];
        #pragma unroll
        for (int i = 0; i < 8; ++i) {
            f32x4 xv = *reinterpret_cast<const f32x4*>(&xs[ng * 8 + i][c4 * 4]);
            acc[i] = fmaf(xv.x, w0, fmaf(xv.y, w1, fmaf(xv.z, w2, fmaf(xv.w, w3, acc[i]))));
        }
    }

    #pragma unroll
    for (int i = 0; i < 8; ++i) ts[ng * 8 + i][f] = f2bf(acc[i]);
    __syncthreads();

    {
        const int col = t >> 1, half = t & 1;
        s16x8 v8;
        #pragma unroll
        for (int i = 0; i < 8; ++i) {
            int n = half * 8 + i;
            v8[i] = (nb + n < N_NODES) ? (short)ts[n][col] : (short)0;
        }
        const int c  = col & 15, ct = col >> 4;
        const int kc = nb >> 5, khalf = (nb >> 4) & 1;
        const int ku = khalf * 2 + half;
        int upair = (kc & 1) * 512 + ct * 64 + c * 4 + ku;
        size_t off = (size_t)(kc >> 1) * 8192 + (size_t)(upair ^ (c & 7)) * 8;
        *reinterpret_cast<s16x8*>(xwt + off) = v8;
    }
}

// ---------------------------------------------------------------------------
// Kernel 2: partial GEMM, split-K (R15 verbatim except: A loads are PLAIN
// (non-nontemporal) -> allow L3 retention of A across graph replays).
// A-loads: one full 1KB row-chunk per instruction (64 lanes x 16B contig,
// row = w*8+j per instruction j=0..7); quad per LOADA; ds_write into ring-6.
// B: gload_lds double-buffer. Plain __syncthreads per tile. P partials bf16.
// ---------------------------------------------------------------------------
#define GLOAD(gsrc, ldst) __builtin_amdgcn_global_load_lds(                      \
    (const __attribute__((address_space(1))) unsigned int*)(gsrc),               \
    (__attribute__((address_space(3))) unsigned int*)(ldst), 16, 0, 0)

#define MFMA_(a, b, c) __builtin_amdgcn_mfma_f32_16x16x32_bf16(a, b, c, 0, 0, 0)

__global__ __launch_bounds__(512, 4) void k_gcn(const float* __restrict__ A,
                                                const unsigned short* __restrict__ xwt,
                                                unsigned short* __restrict__ P) {
    __shared__ __align__(16) unsigned char Bs[2][16384];   // 32 KB
    __shared__ __align__(16) unsigned char As[6][8192];    // 48 KB ring-6

    const int t    = threadIdx.x;
    const int w    = t >> 6;
    const int lane = t & 63;
    const int l16  = lane & 15;
    const int g    = lane >> 4;
    const int mq   = w >> 2;         // 0..1 : 32-row half
    const int cq   = w & 3;          // 0..3 : 32-col quarter
    const int mb    = blockIdx.x % MBLK;
    const int split = blockIdx.x / MBLK;
    const int rbase = mb * BM;
    const int k0    = split * KSPLIT;

    // ---- A staging (per-instruction rows): wave w instr j -> row w*8+j ----
    unsigned arb[8];
    #pragma unroll
    for (int j = 0; j < 8; ++j) {
        int r = rbase + w * 8 + j; if (r > N_NODES - 1) r = N_NODES - 1;
        arb[j] = (unsigned)r * (unsigned)N_NODES + (unsigned)k0;
    }
    const unsigned lq = (unsigned)(lane << 2);   // lane float offset in chunk

    const int asel  = lane >> 4;
    const int aub   = ((lane >> 1) & 7) << 4;
    const int ahalf = (lane & 1) * 8;
    const int awrow = w * 8;                     // + j gives local row

    const unsigned char* const xb  = reinterpret_cast<const unsigned char*>(xwt);
    unsigned char* const AsB = &As[0][0];

    // ---- fragment read byte offsets (R9 verbatim) ----
    int ar00, ar01, ar10, ar11;
    {
        int r0 = mq * 32 + l16, r1 = mq * 32 + 16 + l16;
        ar00 = r0 * 128 + ((0 * 4 + g) ^ (r0 & 7)) * 16;
        ar01 = r0 * 128 + ((1 * 4 + g) ^ (r0 & 7)) * 16;
        ar10 = r1 * 128 + ((0 * 4 + g) ^ (r1 & 7)) * 16;
        ar11 = r1 * 128 + ((1 * 4 + g) ^ (r1 & 7)) * 16;
    }
    int br00, br01, br10, br11;
    {
        int m = l16 & 7;
        br00 = ((0 * 512 + (cq * 2 + 0) * 64 + l16 * 4 + g) ^ m) * 16;
        br01 = ((1 * 512 + (cq * 2 + 0) * 64 + l16 * 4 + g) ^ m) * 16;
        br10 = ((0 * 512 + (cq * 2 + 1) * 64 + l16 * 4 + g) ^ m) * 16;
        br11 = ((1 * 512 + (cq * 2 + 1) * 64 + l16 * 4 + g) ^ m) * 16;
    }

    f32x4 acc00 = {0.f, 0.f, 0.f, 0.f}, acc01 = acc00, acc10 = acc00, acc11 = acc00;
    f32x4 la0, la1, la2, la3, la4, la5, la6, la7;   // 8 x 1KB-row-chunk loads

#define LD1(reg, j, q) do {                                                      \
    unsigned _o = arb[j] + (unsigned)(q) * 256u + lq;                            \
    if (_o > ALIM) _o = ALIM;                                                    \
    reg = *reinterpret_cast<const f32x4*>(A + _o);                               \
} while (0)

#define LOADA(q) do {                                                            \
    LD1(la0, 0, q); LD1(la1, 1, q); LD1(la2, 2, q); LD1(la3, 3, q);              \
    LD1(la4, 4, q); LD1(la5, 5, q); LD1(la6, 6, q); LD1(la7, 7, q);              \
} while (0)

#define WR1(reg, j, s) do {                                                      \
    unsigned char* _p = AsB + (s) * 8192 + (awrow + (j)) * 128                   \
                      + (aub ^ ((j) << 4)) + ahalf;                              \
    *reinterpret_cast<s16x4*>(_p) = pack4(reg);                                  \
} while (0)

#define WRITEA(base) do {                                                        \
    int _s = (base) + asel; if (_s >= 6) _s -= 6;                                \
    WR1(la0, 0, _s); WR1(la1, 1, _s); WR1(la2, 2, _s); WR1(la3, 3, _s);          \
    WR1(la4, 4, _s); WR1(la5, 5, _s); WR1(la6, 6, _s); WR1(la7, 7, _s);          \
} while (0)

#define STAGEB(tile, buf) do {                                                   \
    const unsigned char* _cb = xb + (size_t)(split * 40 + 2 * (tile)) * 8192;    \
    GLOAD(_cb + (w * 2 + 0) * 1024 + lane * 16, &Bs[buf][(w * 2 + 0) * 1024]);   \
    GLOAD(_cb + (w * 2 + 1) * 1024 + lane * 16, &Bs[buf][(w * 2 + 1) * 1024]);   \
} while (0)

#define COMPUTE(slot, buf) do {                                                  \
    const unsigned char* _as = AsB + (slot) * 8192;                              \
    bf16x8 af00 = *reinterpret_cast<const bf16x8*>(_as + ar00);                  \
    bf16x8 af01 = *reinterpret_cast<const bf16x8*>(_as + ar01);                  \
    bf16x8 af10 = *reinterpret_cast<const bf16x8*>(_as + ar10);                  \
    bf16x8 af11 = *reinterpret_cast<const bf16x8*>(_as + ar11);                  \
    bf16x8 bf00 = *reinterpret_cast<const bf16x8*>(&Bs[buf][br00]);              \
    bf16x8 bf01 = *reinterpret_cast<const bf16x8*>(&Bs[buf][br01]);              \
    bf16x8 bf10 = *reinterpret_cast<const bf16x8*>(&Bs[buf][br10]);              \
    bf16x8 bf11 = *reinterpret_cast<const bf16x8*>(&Bs[buf][br11]);              \
    acc00 = MFMA_(af00, bf00, acc00); acc00 = MFMA_(af01, bf01, acc00);          \
    acc01 = MFMA_(af00, bf10, acc01); acc01 = MFMA_(af01, bf11, acc01);          \
    acc10 = MFMA_(af10, bf00, acc10); acc10 = MFMA_(af11, bf01, acc10);          \
    acc11 = MFMA_(af10, bf10, acc11); acc11 = MFMA_(af11, bf11, acc11);          \
} while (0)

    // ---- prologue: quad0 -> slots 0..3; quad1 parked in regs; B tile 0 ----
    LOADA(0);
    STAGEB(0, 0);
    WRITEA(0);         // compiler waits LOADA(0)
    LOADA(1);
    __syncthreads();

    // ---- main loop (R9 greedy schedule, drain barrier per tile) ----
    for (int tile = 0; tile < TPS; ++tile) {
        if (tile + 1 < TPS) STAGEB(tile + 1, (tile + 1) & 1);
        if ((tile & 3) == 2 && tile + 2 < TPS) {
            WRITEA((tile + 2) % 6);
            if (tile <= 10) LOADA((tile + 6) >> 2);
        }
        COMPUTE(tile % 6, tile & 1);
        __syncthreads();
    }

    // ---- write bf16 partials ----
    {
        unsigned short* Pp = P + ((size_t)split * PROWS + rbase) * F;
        #pragma unroll
        for (int e = 0; e < 4; ++e) {
            Pp[(size_t)(mq * 32 +  0 + g * 4 + e) * F + cq * 32 +      l16] = f2bf(acc00[e]);
            Pp[(size_t)(mq * 32 +  0 + g * 4 + e) * F + cq * 32 + 16 + l16] = f2bf(acc01[e]);
            Pp[(size_t)(mq * 32 + 16 + g * 4 + e) * F + cq * 32 +      l16] = f2bf(acc10[e]);
            Pp[(size_t)(mq * 32 + 16 + g * 4 + e) * F + cq * 32 + 16 + l16] = f2bf(acc11[e]);
        }
    }
#undef LD1
#undef LOADA
#undef WR1
#undef WRITEA
#undef STAGEB
#undef COMPUTE
}

// ---------------------------------------------------------------------------
// Kernel 3: out[r] = relu(sum_s bf2f(P[s][r][:]) + b1) . W2 + b2. grid 5000x256.
// ---------------------------------------------------------------------------
__global__ __launch_bounds__(256) void k_red(const unsigned short* __restrict__ P,
                                             const float* __restrict__ b1,
                                             const float* __restrict__ W2,
                                             const float* __restrict__ b2,
                                             float* __restrict__ out) {
    __shared__ float sred[4];
    const int t   = threadIdx.x;
    const int row = blockIdx.x * 2 + (t >> 7);
    const int c   = t & 127;

    float v = 0.f;
    #pragma unroll
    for (int s = 0; s < SPLITS; ++s) {
        unsigned u = P[((size_t)s * PROWS + row) * F + c];
        v += __builtin_bit_cast(float, u << 16);
    }
    v = fmaxf(v + b1[c], 0.f) * W2[c];

    v += __shfl_xor(v, 1);
    v += __shfl_xor(v, 2);
    v += __shfl_xor(v, 4);
    v += __shfl_xor(v, 8);
    v += __shfl_xor(v, 16);
    v += __shfl_xor(v, 32);
    if ((t & 63) == 0) sred[t >> 6] = v;
    __syncthreads();
    if (t < 2) out[blockIdx.x * 2 + t] = sred[t * 2] + sred[t * 2 + 1] + b2[0];
}

extern "C" void kernel_launch(void* const* d_in, const int* in_sizes, int n_in,
                              void* d_out, int out_size, void* d_ws, size_t ws_size,
                              hipStream_t stream) {
    const float* x  = (const float*)d_in[0];
    const float* a  = (const float*)d_in[1];
    const float* W1 = (const float*)d_in[2];
    const float* b1 = (const float*)d_in[3];
    const float* W2 = (const float*)d_in[4];
    const float* b2 = (const float*)d_in[5];
    float* out = (float*)d_out;

    unsigned short* xwt = (unsigned short*)d_ws;                    // 2.62 MB tiled
    unsigned short* P = (unsigned short*)((char*)d_ws + (size_t)(16 << 20)); // bf16 partials

    k_xw<<<640, 256, 0, stream>>>(x, W1, xwt);
    k_gcn<<<MBLK * SPLITS, 512, 0, stream>>>(a, xwt, P);
    k_red<<<5000, 256, 0, stream>>>(P, b1, W2, b2, out);
}